// Round 14
// baseline (115.223 us; speedup 1.0000x reference)
//
#include <hip/hip_runtime.h>
#include <hip/hip_bf16.h>
#include <stdint.h>

#define BB 2
#define SS 4096
#define EE 640
#define HH 4
#define DD 256
#define WIN 512

typedef __attribute__((ext_vector_type(8))) short bv8;    // 8 bf16 (4 VGPR)
typedef __attribute__((ext_vector_type(4))) float fv4;
typedef __attribute__((ext_vector_type(16))) float fv16;  // 32x32 accumulator

__device__ __forceinline__ unsigned short f2b(float f) {
  union { float f; unsigned u; } a; a.f = f;
  unsigned r = a.u + 0x7fffu + ((a.u >> 16) & 1u);   // RNE
  return (unsigned short)(r >> 16);
}
__device__ __forceinline__ float b2f(unsigned short s) {
  union { unsigned u; float f; } a; a.u = ((unsigned)s) << 16;
  return a.f;
}
__device__ __forceinline__ unsigned pk2(float lo, float hi_) {
  return (unsigned)f2b(lo) | ((unsigned)f2b(hi_) << 16);
}

typedef const __attribute__((address_space(1))) unsigned int* as1u;
typedef __attribute__((address_space(3))) unsigned int* as3u;
__device__ __forceinline__ void gld16(const unsigned short* g, unsigned short* l) {
  // async global->LDS, 16B/lane; LDS dst = wave-uniform base + lane*16
  __builtin_amdgcn_global_load_lds((as1u)(const void*)g, (as3u)(void*)l, 16, 0, 0);
}

// ---------------- merged pre-pass: weight transposes + ctab + x cast --------
// z=0..3: weight transposes (f32->bf16). z=4: fragment-ordered cos/sin table
// ctab[s][lr*16+wn2*8+j] = (j<4?cos:sin)[s][wn2*64+(j&3)*16+lr] (f32; uses
// cos[d+128]==cos[d]). z=5: x f32->bf16 cast, grid-stride 1280 fv4/block.
__global__ __launch_bounds__(256) void k_wtrans(const float* __restrict__ Wq,
    const float* __restrict__ Wk, const float* __restrict__ Wv,
    const float* __restrict__ Wo, const float* __restrict__ cosp,
    const float* __restrict__ sinp, const float* __restrict__ x,
    unsigned short* __restrict__ wqkv, unsigned short* __restrict__ wo,
    float* __restrict__ ctab, unsigned short* __restrict__ xb) {
  const int z = blockIdx.z, bx = blockIdx.x, by = blockIdx.y;
  const int t = threadIdx.x;
  if (z == 5) {
    const int bb = bx * 32 + by;          // 0..1023
#pragma unroll
    for (int u = 0; u < 5; ++u) {
      int i = bb * 1280 + u * 256 + t;    // < 1310720
      fv4 v = ((const fv4*)x)[i];
      ushort4 o; o.x = f2b(v.x); o.y = f2b(v.y); o.z = f2b(v.z); o.w = f2b(v.w);
      ((ushort4*)xb)[i] = o;
    }
    return;
  }
  if (z == 4) {
    const int bb = bx * 32 + by;
    const int s = bb * 4 + (t >> 6);
#pragma unroll
    for (int k = 0; k < 4; ++k) {
      int c = (t & 63) * 4 + k;
      int lr = c >> 4, wn2 = (c >> 3) & 1, j = c & 7;
      int d = wn2 * 64 + (j & 3) * 16 + lr;
      float v = (j < 4) ? cosp[(size_t)s * 256 + d] : sinp[(size_t)s * 256 + d];
      ctab[(size_t)s * 256 + c] = v;
    }
    return;
  }
  __shared__ float tile[32][33];
  const float* src; unsigned short* dst; int ss, ds;
  if (z == 0)      { if (bx >= 20 || by >= 32) return; src = Wq; dst = wqkv;              ss = 1024; ds = 640; }
  else if (z == 1) { if (bx >= 20 || by >= 8)  return; src = Wk; dst = wqkv + 1024 * 640; ss = 256;  ds = 640; }
  else if (z == 2) { if (bx >= 20 || by >= 8)  return; src = Wv; dst = wqkv + 1280 * 640; ss = 256;  ds = 640; }
  else             { if (bx >= 32 || by >= 20) return; src = Wo; dst = wo;                ss = 640;  ds = 1024; }
  int r0 = bx * 32, c0 = by * 32;
  int rr = t >> 3, cc = (t & 7) * 4;
  fv4 xv = *(const fv4*)(src + (size_t)(r0 + rr) * ss + c0 + cc);
#pragma unroll
  for (int i = 0; i < 4; ++i) tile[cc + i][rr] = xv[i];
  __syncthreads();
  ushort4 o;
  o.x = f2b(tile[rr][cc + 0]); o.y = f2b(tile[rr][cc + 1]);
  o.z = f2b(tile[rr][cc + 2]); o.w = f2b(tile[rr][cc + 3]);
  *(ushort4*)(dst + (size_t)(c0 + rr) * ds + r0 + cc) = o;
}

// ---------------- fused QKV GEMM + RMSNorm + RoPE + V-transpose -------------
// C(8192x1536) = xb * wqkv^T, tiles 64x256 aligned to heads (nt 0-3 q, 4 k,
// 5 v). Wave col-split: wave owns cols {wn2*64..+63} U {+128} so RoPE
// partners (d, d+128) are IN-THREAD (acc ni and ni^4). RMS via shfl_xor over
// the 16-lane group + rsum exchange — no LDS transpose for q/k. cos/sin from
// fragment-ordered f32 ctab. V: packed b64 col-major LDS transpose. MFMA
// loop = proven dbuf + counted-vmcnt pattern.
__global__ __launch_bounds__(256) void k_gemm_qkv(const unsigned short* __restrict__ A,
    const unsigned short* __restrict__ Bt, const float* __restrict__ ctab,
    const float* __restrict__ qsc, const float* __restrict__ ksc,
    unsigned short* __restrict__ qo, unsigned short* __restrict__ ko,
    unsigned short* __restrict__ vt) {
  __shared__ __align__(16) char shl[40960];   // staging 40KB; epilogue reuse
  unsigned short* la = (unsigned short*)shl;                 // [2][64*32] 8KB
  unsigned short* lb = (unsigned short*)(shl + 8192);        // [2][256*32] 32KB
  const int K = EE;
  const int bid = blockIdx.x;
  const int gidx = (bid & 7) * 96 + (bid >> 3);   // XCD-chunked (768 = 8*96)
  const int mt = gidx / 6, nt = gidx % 6;
  const int m0 = mt * 64, n0 = nt * 256;
  const int tid = threadIdx.x, lane = tid & 63, wave = tid >> 6;
  const int g = lane >> 4, lr = lane & 15;
  const int wm = (wave >> 1) * 32, wn2 = wave & 1;
  fv4 acc[2][8] = {};
  const unsigned short* ga0 = A + (size_t)(m0 + (tid >> 2)) * K + (tid & 3) * 8;
  const unsigned short* gb0 = Bt + (size_t)(n0 + (tid >> 2)) * K + (tid & 3) * 8;
  auto stage = [&](int k0, int pp) {
    gld16(ga0 + k0, la + pp * 2048 + wave * 512);
#pragma unroll
    for (int c = 0; c < 4; ++c)
      gld16(gb0 + (size_t)(c * 64) * K + k0, lb + pp * 8192 + (c * 64 + wave * 16) * 32);
  };
  stage(0, 0);
  const int NIT = K >> 5;   // 20
  for (int it = 0; it < NIT; ++it) {
    const int p = it & 1;
    if (it > 0) __builtin_amdgcn_s_barrier();
    if (it + 1 < NIT) {
      stage((it + 1) * 32, p ^ 1);
      asm volatile("s_waitcnt vmcnt(5)" ::: "memory");   // stage(it) landed
    } else {
      asm volatile("s_waitcnt vmcnt(0)" ::: "memory");
    }
    __builtin_amdgcn_sched_barrier(0);
    __builtin_amdgcn_s_barrier();
    bv8 af[2], bf[8];
#pragma unroll
    for (int mi = 0; mi < 2; ++mi)
      af[mi] = *(const bv8*)(la + p * 2048 + (wm + mi * 16 + lr) * 32 + g * 8);
#pragma unroll
    for (int ni = 0; ni < 8; ++ni) {
      int coln = wn2 * 64 + (ni & 3) * 16 + (ni >> 2) * 128 + lr;
      bf[ni] = *(const bv8*)(lb + p * 8192 + coln * 32 + g * 8);
    }
    __builtin_amdgcn_s_setprio(1);
#pragma unroll
    for (int mi = 0; mi < 2; ++mi)
#pragma unroll
      for (int ni = 0; ni < 8; ++ni)
        acc[mi][ni] = __builtin_amdgcn_mfma_f32_16x16x32_bf16(af[mi], bf[ni], acc[mi][ni], 0, 0, 0);
    __builtin_amdgcn_s_setprio(0);
  }
  __syncthreads();                       // staging reads done; LDS reusable
  if (nt < 5) {
    float* rsum = (float*)(shl + 36864);  // [64][2]
    float part[2][4];
#pragma unroll
    for (int mi = 0; mi < 2; ++mi)
#pragma unroll
      for (int r = 0; r < 4; ++r) {
        float ss2 = 0.f;
#pragma unroll
        for (int ni = 0; ni < 8; ++ni) ss2 += acc[mi][ni][r] * acc[mi][ni][r];
        part[mi][r] = ss2;
      }
#pragma unroll
    for (int off = 1; off < 16; off <<= 1)
#pragma unroll
      for (int mi = 0; mi < 2; ++mi)
#pragma unroll
        for (int r = 0; r < 4; ++r) part[mi][r] += __shfl_xor(part[mi][r], off, 64);
    if (lr == 0) {
#pragma unroll
      for (int mi = 0; mi < 2; ++mi)
#pragma unroll
        for (int r = 0; r < 4; ++r)
          rsum[(wm + mi * 16 + g * 4 + r) * 2 + wn2] = part[mi][r];
    }
    __syncthreads();
    const float* scp = (nt < 4) ? qsc : ksc;
    const float mult = (nt < 4) ? (0.0625f * 1.44269504f) : 1.0f;
    float scl[8];
#pragma unroll
    for (int ni = 0; ni < 8; ++ni) {
      int d = wn2 * 64 + (ni & 3) * 16 + (ni >> 2) * 128 + lr;
      scl[ni] = 1.0f + scp[d];
    }
#pragma unroll
    for (int mi = 0; mi < 2; ++mi)
#pragma unroll
      for (int r = 0; r < 4; ++r) {
        int row = wm + mi * 16 + g * 4 + r;
        int mabs = m0 + row;
        int bb = mabs >> 12, s = mabs & 4095;
        float tot = rsum[row * 2 + 0] + rsum[row * 2 + 1];
        float rs = rsqrtf(tot * (1.0f / 256.0f) + 1e-6f);
        fv4 c4 = *(const fv4*)(ctab + (size_t)s * 256 + lr * 16 + wn2 * 8);
        fv4 s4 = *(const fv4*)(ctab + (size_t)s * 256 + lr * 16 + wn2 * 8 + 4);
        unsigned short* dst = (nt < 4)
            ? qo + ((size_t)(bb * HH + nt) * SS + s) * 256
            : ko + ((size_t)bb * SS + s) * 256;
#pragma unroll
        for (int j = 0; j < 4; ++j) {
          float nlo = acc[mi][j][r] * rs * scl[j];
          float nhi = acc[mi][j + 4][r] * rs * scl[j + 4];
          float olo = (nlo * c4[j] - nhi * s4[j]) * mult;
          float ohi = (nhi * c4[j] + nlo * s4[j]) * mult;
          int dlo = wn2 * 64 + j * 16 + lr;
          dst[dlo] = f2b(olo);
          dst[dlo + 128] = f2b(ohi);
        }
      }
  } else {
    unsigned short* vcol = (unsigned short*)shl;   // [256][72]
#pragma unroll
    for (int mi = 0; mi < 2; ++mi)
#pragma unroll
      for (int ni = 0; ni < 8; ++ni) {
        int col = wn2 * 64 + (ni & 3) * 16 + (ni >> 2) * 128 + lr;
        int row0 = wm + mi * 16 + g * 4;
        uint2 u;
        u.x = pk2(acc[mi][ni][0], acc[mi][ni][1]);
        u.y = pk2(acc[mi][ni][2], acc[mi][ni][3]);
        *(uint2*)(vcol + col * 72 + row0) = u;
      }
    __syncthreads();
    const int d = tid;
    const int bb0 = m0 >> 12, s0 = m0 & 4095;
    unsigned short* dst = vt + ((size_t)bb0 * 256 + d) * SS + s0;
#pragma unroll
    for (int c8 = 0; c8 < 8; ++c8) {
      bv8 v = *(const bv8*)(vcol + d * 72 + c8 * 8);
      *(bv8*)(dst + c8 * 8) = v;
    }
  }
}

// ---------------- out-proj GEMM (R12-proven): C = A * Bt^T, 128x64 tile -----
template <bool OUT_BF16, int BN>
__global__ __launch_bounds__(256) void k_gemm(const unsigned short* __restrict__ A,
    const unsigned short* __restrict__ Bt, void* __restrict__ Cp,
    int M, int N, int K, int nt_n) {
  __shared__ unsigned short la[2][128 * 32];
  __shared__ unsigned short lb[2][BN * 32];
  const int bid = blockIdx.x;
  const int gidx = (bid & 7) * (gridDim.x >> 3) + (bid >> 3);
  const int m0 = (gidx / nt_n) * 128, n0 = (gidx % nt_n) * BN;
  const int tid = threadIdx.x, lane = tid & 63, wave = tid >> 6;
  const int g = lane >> 4, lr = lane & 15;
  constexpr int MI = (BN == 128) ? 4 : 2;
  const int wm = (BN == 128) ? (wave >> 1) * 64 : wave * 32;
  const int wn = (BN == 128) ? (wave & 1) * 64 : 0;
  fv4 acc[MI][4] = {};
  const int srow = wave * 32 + (lane >> 2);
  const int sch = (lane & 3) * 8;
  const unsigned short* ga0 = A + (size_t)(m0 + srow) * K + sch;
  const int srowb = (BN == 128) ? srow : (wave * 16 + (lane >> 2));
  const unsigned short* gb0 = Bt + (size_t)(n0 + srowb) * K + sch;
  const int NIT = K >> 5;
  auto stage = [&](int k0, int pp) {
    unsigned short* lad = la[pp] + wave * 1024;
    unsigned short* lbd = lb[pp] + ((BN == 128) ? wave * 1024 : wave * 512);
    gld16(ga0 + k0, lad);
    gld16(ga0 + (size_t)16 * K + k0, lad + 512);
    gld16(gb0 + k0, lbd);
    if constexpr (BN == 128) gld16(gb0 + (size_t)16 * K + k0, lbd + 512);
  };
  stage(0, 0);
  for (int it = 0; it < NIT; ++it) {
    const int p = it & 1;
    if (it > 0) __builtin_amdgcn_s_barrier();
    if (it + 1 < NIT) {
      stage((it + 1) * 32, p ^ 1);
      if constexpr (BN == 128)
        asm volatile("s_waitcnt vmcnt(4)" ::: "memory");
      else
        asm volatile("s_waitcnt vmcnt(3)" ::: "memory");
    } else {
      asm volatile("s_waitcnt vmcnt(0)" ::: "memory");
    }
    __builtin_amdgcn_sched_barrier(0);
    __builtin_amdgcn_s_barrier();
    bv8 af[MI], bf[4];
#pragma unroll
    for (int mi = 0; mi < MI; ++mi)
      af[mi] = *(const bv8*)(la[p] + (wm + mi * 16 + lr) * 32 + g * 8);
#pragma unroll
    for (int ni = 0; ni < 4; ++ni)
      bf[ni] = *(const bv8*)(lb[p] + (wn + ni * 16 + lr) * 32 + g * 8);
    __builtin_amdgcn_s_setprio(1);
#pragma unroll
    for (int mi = 0; mi < MI; ++mi)
#pragma unroll
      for (int ni = 0; ni < 4; ++ni)
        acc[mi][ni] = __builtin_amdgcn_mfma_f32_16x16x32_bf16(af[mi], bf[ni], acc[mi][ni], 0, 0, 0);
    __builtin_amdgcn_s_setprio(0);
  }
#pragma unroll
  for (int mi = 0; mi < MI; ++mi) {
#pragma unroll
    for (int r = 0; r < 4; ++r) {
      size_t row = (size_t)(m0 + wm + mi * 16 + g * 4 + r);
#pragma unroll
      for (int ni = 0; ni < 4; ++ni) {
        int col = n0 + wn + ni * 16 + lr;
        float val = acc[mi][ni][r];
        if constexpr (OUT_BF16)
          ((unsigned short*)Cp)[row * N + col] = f2b(val);
        else
          ((float*)Cp)[row * N + col] = val;
      }
    }
  }
}

// ---------------- flash attention, sliding window 512 ----------------------
// MQA-shared (best measured structure): block = 512 thr = 8 waves = 4 heads x
// 2 key-halves over a 32-q-row slab; K/V staged once serve all 4 heads.
// 32x32x16 MFMA, swapped operands (S^T = mfma(K,Q)), in-register P via manual
// pack + permlane32_swap. Softmax in exp2 domain (log2e folded into q); fixed
// max (|score*log2e| <= 23.1, Cauchy-Schwarz on RMSNorm'd vectors). K+V
// double-buffered via global_load_lds with both-sides XOR swizzle.
// R14: softmax split per-m2 and interleaved into the PV loop — PV's first 8
// MFMAs start after only half the exp2/pack work; the other half's VALU prep
// overlaps m2=0's MFMAs (shortens the serial QK->PV critical path).
__global__ __launch_bounds__(512, 2) void k_attn(const unsigned short* __restrict__ q,
    const unsigned short* __restrict__ kg, const unsigned short* __restrict__ vtg,
    unsigned short* __restrict__ att) {
  __shared__ __align__(16) char ldsbuf[133120];   // K/V tiles; reused as combine buf
  __shared__ float lsb[4][32];
  unsigned short* kt = (unsigned short*)ldsbuf;           // [2][64*256]
  unsigned short* vl = (unsigned short*)ldsbuf + 32768;   // [2][256*64]
  const int bid = blockIdx.x;
  const int gidx = (bid & 7) * 32 + (bid >> 3);
  const int b = gidx >> 7;
  const int i0 = (gidx & 127) * 32;
  const int tid = threadIdx.x, wave = tid >> 6, lane = tid & 63;
  const int h = wave >> 1, ks = wave & 1;
  const int hi = lane >> 5, l31 = lane & 31;
  bv8 qf[16];
  {
    const unsigned short* qp = q + ((size_t)(b * HH + h) * SS + i0 + l31) * 256;
#pragma unroll
    for (int m = 0; m < 16; ++m) qf[m] = *(const bv8*)(qp + m * 16 + hi * 8);
  }
  fv16 po[8] = {};
  float lsp = 0.f;
  const int t0 = (i0 >= WIN) ? ((i0 - WIN + 1) >> 6) : 0;
  const int t1 = i0 >> 6;
  const unsigned short* kb = kg + (size_t)b * SS * 256;
  const unsigned short* vb = vtg + (size_t)b * 256 * SS;
  auto stageK = [&](int t, int pp) {
    const unsigned short* kbase = kb + (size_t)t * 64 * 256;
    unsigned short* dst = kt + pp * 16384;
#pragma unroll
    for (int c = 0; c < 4; ++c) {
      int slot = c * 512 + tid;
      int row = slot >> 5, s = slot & 31;
      gld16(kbase + (size_t)row * 256 + ((s ^ (row & 7)) * 8),
            dst + (c * 512 + wave * 64) * 8);
    }
  };
  auto stageV = [&](int t, int pp) {
    const unsigned short* vbase = vb + (size_t)t * 64;
    unsigned short* dst = vl + pp * 16384;
#pragma unroll
    for (int c = 0; c < 4; ++c) {
      int slot = c * 512 + tid;
      int d_ = slot >> 3, s = slot & 7;
      gld16(vbase + (size_t)d_ * SS + ((s ^ (d_ & 7)) * 8),
            dst + (c * 512 + wave * 64) * 8);
    }
  };
  stageK(t0, 0); stageV(t0, 0);
  int p = 0;
  const int krow = ks * 32 + l31;
  const int krx = krow & 7;
  const int vrx = l31 & 7;
  const float FSUB = 16.5f * 1.44269504f;
  for (int t = t0; t <= t1; ++t) {
    __syncthreads();
    if (t < t1) { stageK(t + 1, p ^ 1); stageV(t + 1, p ^ 1); }
    fv16 sa = {};
    const unsigned short* ktp = kt + p * 16384 + krow * 256;
    __builtin_amdgcn_s_setprio(1);
#pragma unroll
    for (int m = 0; m < 16; ++m) {
      bv8 kf = *(const bv8*)(ktp + (((m * 2 + hi) ^ krx) * 8));
      sa = __builtin_amdgcn_mfma_f32_32x32x16_bf16(kf, qf[m], sa, 0, 0, 0);
    }
    __builtin_amdgcn_s_setprio(0);
    const int kb0 = t * 64 + ks * 32;
    const bool nm = (kb0 + 31 > i0) || (i0 + 31 - kb0 >= WIN);
    if (nm) {
      const int qa = i0 + l31;
#pragma unroll
      for (int r = 0; r < 16; ++r) {
        int j = kb0 + (r & 3) + 8 * (r >> 2) + 4 * hi;
        if (j > qa || qa - j >= WIN) sa[r] = -1e30f;
      }
    }
    const unsigned short* vlp = vl + p * 16384;
#pragma unroll
    for (int m2 = 0; m2 < 2; ++m2) {
      // per-m2 softmax slice: 8 exp2 + 4 pack + 2 permlane, then 8 MFMAs.
      float e0 = exp2f(sa[8 * m2 + 0] - FSUB);
      float e1 = exp2f(sa[8 * m2 + 1] - FSUB);
      float e2 = exp2f(sa[8 * m2 + 2] - FSUB);
      float e3 = exp2f(sa[8 * m2 + 3] - FSUB);
      float e4 = exp2f(sa[8 * m2 + 4] - FSUB);
      float e5 = exp2f(sa[8 * m2 + 5] - FSUB);
      float e6 = exp2f(sa[8 * m2 + 6] - FSUB);
      float e7 = exp2f(sa[8 * m2 + 7] - FSUB);
      lsp += (e0 + e1) + (e2 + e3) + (e4 + e5) + (e6 + e7);
      unsigned b0 = pk2(e0, e1), b1 = pk2(e2, e3);
      unsigned b2 = pk2(e4, e5), b3 = pk2(e6, e7);
      auto r02 = __builtin_amdgcn_permlane32_swap(b0, b2, false, false);
      auto r13 = __builtin_amdgcn_permlane32_swap(b1, b3, false, false);
      union { unsigned u[4]; bv8 v; } pf;
      pf.u[0] = r02[0]; pf.u[1] = r13[0]; pf.u[2] = r02[1]; pf.u[3] = r13[1];
      const int slot = (ks * 4 + m2 * 2 + hi) ^ vrx;
      __builtin_amdgcn_s_setprio(1);
#pragma unroll
      for (int ds_ = 0; ds_ < 8; ++ds_) {
        bv8 vf = *(const bv8*)(vlp + (ds_ * 32 + l31) * 64 + slot * 8);
        po[ds_] = __builtin_amdgcn_mfma_f32_32x32x16_bf16(vf, pf.v, po[ds_], 0, 0, 0);
      }
      __builtin_amdgcn_s_setprio(0);
    }
    p ^= 1;
  }
  float lsfull = lsp + __shfl_xor(lsp, 32, 64);
  __syncthreads();
  float* cb = (float*)ldsbuf;
  if (ks == 1) {
#pragma unroll
    for (int ds_ = 0; ds_ < 8; ++ds_)
#pragma unroll
      for (int j = 0; j < 4; ++j) {
        int d0 = ds_ * 32 + 8 * j + 4 * hi;
        fv4 v4; v4[0] = po[ds_][4 * j]; v4[1] = po[ds_][4 * j + 1];
        v4[2] = po[ds_][4 * j + 2]; v4[3] = po[ds_][4 * j + 3];
        *(fv4*)(cb + (h * 32 + l31) * 260 + d0) = v4;
      }
    if (lane < 32) lsb[h][lane] = lsfull;
  }
  __syncthreads();
  if (ks == 0) {
    float total = lsfull + lsb[h][l31];
    float inv = 1.0f / total;
    unsigned short* op = att + ((size_t)b * SS + i0 + l31) * 1024 + h * 256;
#pragma unroll
    for (int ds_ = 0; ds_ < 8; ++ds_)
#pragma unroll
      for (int j = 0; j < 4; ++j) {
        int d0 = ds_ * 32 + 8 * j + 4 * hi;
        fv4 v4 = *(const fv4*)(cb + (h * 32 + l31) * 260 + d0);
        ushort4 o;
        o.x = f2b((po[ds_][4 * j] + v4[0]) * inv);
        o.y = f2b((po[ds_][4 * j + 1] + v4[1]) * inv);
        o.z = f2b((po[ds_][4 * j + 2] + v4[2]) * inv);
        o.w = f2b((po[ds_][4 * j + 3] + v4[3]) * inv);
        *(ushort4*)(op + d0) = o;
      }
  }
}

extern "C" void kernel_launch(void* const* d_in, const int* in_sizes, int n_in,
                              void* d_out, int out_size, void* d_ws, size_t ws_size,
                              hipStream_t stream) {
  const float* x    = (const float*)d_in[0];
  // d_in[1] = mask (computed analytically)
  const float* cosp = (const float*)d_in[2];
  const float* sinp = (const float*)d_in[3];
  const float* Wq   = (const float*)d_in[4];
  const float* Wk   = (const float*)d_in[5];
  const float* Wv   = (const float*)d_in[6];
  const float* Wo   = (const float*)d_in[7];
  const float* qsc  = (const float*)d_in[8];
  const float* ksc  = (const float*)d_in[9];
  float* out = (float*)d_out;
  char* ws = (char*)d_ws;

  unsigned short* xb   = (unsigned short*)(ws);               // 8192x640 bf16
  unsigned short* wqkv = (unsigned short*)(ws + 10485760);    // 1536x640 bf16 (W^T)
  unsigned short* wo   = (unsigned short*)(ws + 12451840);    // 640x1024 bf16 (Wo^T)
  float*          ctab = (float*)(ws + 13762560);             // 4096x256 f32
  unsigned short* qb   = (unsigned short*)(ws + 38928384);    // (B,H,S,D) bf16
  unsigned short* kbuf = (unsigned short*)(ws + 55705600);    // (B,S,D) bf16
  unsigned short* vt   = (unsigned short*)(ws + 59899904);    // (B,D,S) bf16
  unsigned short* attb = (unsigned short*)(ws + 64094208);    // (B,S,H*D) bf16

  k_wtrans<<<dim3(32, 32, 6), 256, 0, stream>>>(Wq, Wk, Wv, Wo, cosp, sinp, x,
                                                wqkv, wo, ctab, xb);
  k_gemm_qkv<<<768, 256, 0, stream>>>(xb, wqkv, ctab, qsc, ksc, qb, kbuf, vt);
  k_attn<<<256, 512, 0, stream>>>(qb, kbuf, vt, attb);
  k_gemm<false, 64><<<640, 256, 0, stream>>>(attb, wo, out, 8192, 640, 1024, 10);
}

// Round 15
// 110.013 us; speedup vs baseline: 1.0474x; 1.0474x over previous
//
#include <hip/hip_runtime.h>
#include <hip/hip_bf16.h>
#include <stdint.h>

#define BB 2
#define SS 4096
#define EE 640
#define HH 4
#define DD 256
#define WIN 512

typedef __attribute__((ext_vector_type(8))) short bv8;    // 8 bf16 (4 VGPR)
typedef __attribute__((ext_vector_type(4))) float fv4;
typedef __attribute__((ext_vector_type(16))) float fv16;  // 32x32 accumulator

__device__ __forceinline__ unsigned short f2b(float f) {
  union { float f; unsigned u; } a; a.f = f;
  unsigned r = a.u + 0x7fffu + ((a.u >> 16) & 1u);   // RNE
  return (unsigned short)(r >> 16);
}
__device__ __forceinline__ float b2f(unsigned short s) {
  union { unsigned u; float f; } a; a.u = ((unsigned)s) << 16;
  return a.f;
}
__device__ __forceinline__ unsigned pk2(float lo, float hi_) {
  return (unsigned)f2b(lo) | ((unsigned)f2b(hi_) << 16);
}

typedef const __attribute__((address_space(1))) unsigned int* as1u;
typedef __attribute__((address_space(3))) unsigned int* as3u;
__device__ __forceinline__ void gld16(const unsigned short* g, unsigned short* l) {
  // async global->LDS, 16B/lane; LDS dst = wave-uniform base + lane*16
  __builtin_amdgcn_global_load_lds((as1u)(const void*)g, (as3u)(void*)l, 16, 0, 0);
}

// ---------------- merged pre-pass: weight transposes + ctab + x cast --------
// z=0..3: weight transposes (f32->bf16). z=4: fragment-ordered cos/sin table
// ctab[s][lr*16+wn2*8+j] = (j<4?cos:sin)[s][wn2*64+(j&3)*16+lr] (f32; uses
// cos[d+128]==cos[d]). z=5: x f32->bf16 cast, 1280 fv4/block.
__global__ __launch_bounds__(256) void k_wtrans(const float* __restrict__ Wq,
    const float* __restrict__ Wk, const float* __restrict__ Wv,
    const float* __restrict__ Wo, const float* __restrict__ cosp,
    const float* __restrict__ sinp, const float* __restrict__ x,
    unsigned short* __restrict__ wqkv, unsigned short* __restrict__ wo,
    float* __restrict__ ctab, unsigned short* __restrict__ xb) {
  const int z = blockIdx.z, bx = blockIdx.x, by = blockIdx.y;
  const int t = threadIdx.x;
  if (z == 5) {
    const int bb = bx * 32 + by;          // 0..1023
#pragma unroll
    for (int u = 0; u < 5; ++u) {
      int i = bb * 1280 + u * 256 + t;    // < 1310720
      fv4 v = ((const fv4*)x)[i];
      ushort4 o; o.x = f2b(v.x); o.y = f2b(v.y); o.z = f2b(v.z); o.w = f2b(v.w);
      ((ushort4*)xb)[i] = o;
    }
    return;
  }
  if (z == 4) {
    const int bb = bx * 32 + by;
    const int s = bb * 4 + (t >> 6);
#pragma unroll
    for (int k = 0; k < 4; ++k) {
      int c = (t & 63) * 4 + k;
      int lr = c >> 4, wn2 = (c >> 3) & 1, j = c & 7;
      int d = wn2 * 64 + (j & 3) * 16 + lr;
      float v = (j < 4) ? cosp[(size_t)s * 256 + d] : sinp[(size_t)s * 256 + d];
      ctab[(size_t)s * 256 + c] = v;
    }
    return;
  }
  __shared__ float tile[32][33];
  const float* src; unsigned short* dst; int ss, ds;
  if (z == 0)      { if (bx >= 20 || by >= 32) return; src = Wq; dst = wqkv;              ss = 1024; ds = 640; }
  else if (z == 1) { if (bx >= 20 || by >= 8)  return; src = Wk; dst = wqkv + 1024 * 640; ss = 256;  ds = 640; }
  else if (z == 2) { if (bx >= 20 || by >= 8)  return; src = Wv; dst = wqkv + 1280 * 640; ss = 256;  ds = 640; }
  else             { if (bx >= 32 || by >= 20) return; src = Wo; dst = wo;                ss = 640;  ds = 1024; }
  int r0 = bx * 32, c0 = by * 32;
  int rr = t >> 3, cc = (t & 7) * 4;
  fv4 xv = *(const fv4*)(src + (size_t)(r0 + rr) * ss + c0 + cc);
#pragma unroll
  for (int i = 0; i < 4; ++i) tile[cc + i][rr] = xv[i];
  __syncthreads();
  ushort4 o;
  o.x = f2b(tile[rr][cc + 0]); o.y = f2b(tile[rr][cc + 1]);
  o.z = f2b(tile[rr][cc + 2]); o.w = f2b(tile[rr][cc + 3]);
  *(ushort4*)(dst + (size_t)(c0 + rr) * ds + r0 + cc) = o;
}

// ---------------- fused QKV GEMM + RMSNorm + RoPE + V-transpose -------------
// (R12-proven) C(8192x1536) = xb * wqkv^T, tiles 64x256 aligned to heads
// (nt 0-3 q, 4 k, 5 v). Wave col-split: wave owns cols {wn2*64..+63} U {+128}
// so RoPE partners (d, d+128) are IN-THREAD (acc ni and ni^4). RMS via
// shfl_xor over the 16-lane group + rsum exchange. cos/sin from fragment-
// ordered f32 ctab. V: packed b64 col-major LDS transpose. MFMA loop = dbuf +
// counted-vmcnt pattern.
__global__ __launch_bounds__(256) void k_gemm_qkv(const unsigned short* __restrict__ A,
    const unsigned short* __restrict__ Bt, const float* __restrict__ ctab,
    const float* __restrict__ qsc, const float* __restrict__ ksc,
    unsigned short* __restrict__ qo, unsigned short* __restrict__ ko,
    unsigned short* __restrict__ vt) {
  __shared__ __align__(16) char shl[40960];   // staging 40KB; epilogue reuse
  unsigned short* la = (unsigned short*)shl;                 // [2][64*32] 8KB
  unsigned short* lb = (unsigned short*)(shl + 8192);        // [2][256*32] 32KB
  const int K = EE;
  const int bid = blockIdx.x;
  const int gidx = (bid & 7) * 96 + (bid >> 3);   // XCD-chunked (768 = 8*96)
  const int mt = gidx / 6, nt = gidx % 6;
  const int m0 = mt * 64, n0 = nt * 256;
  const int tid = threadIdx.x, lane = tid & 63, wave = tid >> 6;
  const int g = lane >> 4, lr = lane & 15;
  const int wm = (wave >> 1) * 32, wn2 = wave & 1;
  fv4 acc[2][8] = {};
  const unsigned short* ga0 = A + (size_t)(m0 + (tid >> 2)) * K + (tid & 3) * 8;
  const unsigned short* gb0 = Bt + (size_t)(n0 + (tid >> 2)) * K + (tid & 3) * 8;
  auto stage = [&](int k0, int pp) {
    gld16(ga0 + k0, la + pp * 2048 + wave * 512);
#pragma unroll
    for (int c = 0; c < 4; ++c)
      gld16(gb0 + (size_t)(c * 64) * K + k0, lb + pp * 8192 + (c * 64 + wave * 16) * 32);
  };
  stage(0, 0);
  const int NIT = K >> 5;   // 20
  for (int it = 0; it < NIT; ++it) {
    const int p = it & 1;
    if (it > 0) __builtin_amdgcn_s_barrier();
    if (it + 1 < NIT) {
      stage((it + 1) * 32, p ^ 1);
      asm volatile("s_waitcnt vmcnt(5)" ::: "memory");   // stage(it) landed
    } else {
      asm volatile("s_waitcnt vmcnt(0)" ::: "memory");
    }
    __builtin_amdgcn_sched_barrier(0);
    __builtin_amdgcn_s_barrier();
    bv8 af[2], bf[8];
#pragma unroll
    for (int mi = 0; mi < 2; ++mi)
      af[mi] = *(const bv8*)(la + p * 2048 + (wm + mi * 16 + lr) * 32 + g * 8);
#pragma unroll
    for (int ni = 0; ni < 8; ++ni) {
      int coln = wn2 * 64 + (ni & 3) * 16 + (ni >> 2) * 128 + lr;
      bf[ni] = *(const bv8*)(lb + p * 8192 + coln * 32 + g * 8);
    }
    __builtin_amdgcn_s_setprio(1);
#pragma unroll
    for (int mi = 0; mi < 2; ++mi)
#pragma unroll
      for (int ni = 0; ni < 8; ++ni)
        acc[mi][ni] = __builtin_amdgcn_mfma_f32_16x16x32_bf16(af[mi], bf[ni], acc[mi][ni], 0, 0, 0);
    __builtin_amdgcn_s_setprio(0);
  }
  __syncthreads();                       // staging reads done; LDS reusable
  if (nt < 5) {
    float* rsum = (float*)(shl + 36864);  // [64][2]
    float part[2][4];
#pragma unroll
    for (int mi = 0; mi < 2; ++mi)
#pragma unroll
      for (int r = 0; r < 4; ++r) {
        float ss2 = 0.f;
#pragma unroll
        for (int ni = 0; ni < 8; ++ni) ss2 += acc[mi][ni][r] * acc[mi][ni][r];
        part[mi][r] = ss2;
      }
#pragma unroll
    for (int off = 1; off < 16; off <<= 1)
#pragma unroll
      for (int mi = 0; mi < 2; ++mi)
#pragma unroll
        for (int r = 0; r < 4; ++r) part[mi][r] += __shfl_xor(part[mi][r], off, 64);
    if (lr == 0) {
#pragma unroll
      for (int mi = 0; mi < 2; ++mi)
#pragma unroll
        for (int r = 0; r < 4; ++r)
          rsum[(wm + mi * 16 + g * 4 + r) * 2 + wn2] = part[mi][r];
    }
    __syncthreads();
    const float* scp = (nt < 4) ? qsc : ksc;
    const float mult = (nt < 4) ? (0.0625f * 1.44269504f) : 1.0f;
    float scl[8];
#pragma unroll
    for (int ni = 0; ni < 8; ++ni) {
      int d = wn2 * 64 + (ni & 3) * 16 + (ni >> 2) * 128 + lr;
      scl[ni] = 1.0f + scp[d];
    }
#pragma unroll
    for (int mi = 0; mi < 2; ++mi)
#pragma unroll
      for (int r = 0; r < 4; ++r) {
        int row = wm + mi * 16 + g * 4 + r;
        int mabs = m0 + row;
        int bb = mabs >> 12, s = mabs & 4095;
        float tot = rsum[row * 2 + 0] + rsum[row * 2 + 1];
        float rs = rsqrtf(tot * (1.0f / 256.0f) + 1e-6f);
        fv4 c4 = *(const fv4*)(ctab + (size_t)s * 256 + lr * 16 + wn2 * 8);
        fv4 s4 = *(const fv4*)(ctab + (size_t)s * 256 + lr * 16 + wn2 * 8 + 4);
        unsigned short* dst = (nt < 4)
            ? qo + ((size_t)(bb * HH + nt) * SS + s) * 256
            : ko + ((size_t)bb * SS + s) * 256;
#pragma unroll
        for (int j = 0; j < 4; ++j) {
          float nlo = acc[mi][j][r] * rs * scl[j];
          float nhi = acc[mi][j + 4][r] * rs * scl[j + 4];
          float olo = (nlo * c4[j] - nhi * s4[j]) * mult;
          float ohi = (nhi * c4[j] + nlo * s4[j]) * mult;
          int dlo = wn2 * 64 + j * 16 + lr;
          dst[dlo] = f2b(olo);
          dst[dlo + 128] = f2b(ohi);
        }
      }
  } else {
    unsigned short* vcol = (unsigned short*)shl;   // [256][72]
#pragma unroll
    for (int mi = 0; mi < 2; ++mi)
#pragma unroll
      for (int ni = 0; ni < 8; ++ni) {
        int col = wn2 * 64 + (ni & 3) * 16 + (ni >> 2) * 128 + lr;
        int row0 = wm + mi * 16 + g * 4;
        uint2 u;
        u.x = pk2(acc[mi][ni][0], acc[mi][ni][1]);
        u.y = pk2(acc[mi][ni][2], acc[mi][ni][3]);
        *(uint2*)(vcol + col * 72 + row0) = u;
      }
    __syncthreads();
    const int d = tid;
    const int bb0 = m0 >> 12, s0 = m0 & 4095;
    unsigned short* dst = vt + ((size_t)bb0 * 256 + d) * SS + s0;
#pragma unroll
    for (int c8 = 0; c8 < 8; ++c8) {
      bv8 v = *(const bv8*)(vcol + d * 72 + c8 * 8);
      *(bv8*)(dst + c8 * 8) = v;
    }
  }
}

// ---------------- out-proj GEMM (R12-proven): C = A * Bt^T, 128x64 tile -----
template <bool OUT_BF16, int BN>
__global__ __launch_bounds__(256) void k_gemm(const unsigned short* __restrict__ A,
    const unsigned short* __restrict__ Bt, void* __restrict__ Cp,
    int M, int N, int K, int nt_n) {
  __shared__ unsigned short la[2][128 * 32];
  __shared__ unsigned short lb[2][BN * 32];
  const int bid = blockIdx.x;
  const int gidx = (bid & 7) * (gridDim.x >> 3) + (bid >> 3);
  const int m0 = (gidx / nt_n) * 128, n0 = (gidx % nt_n) * BN;
  const int tid = threadIdx.x, lane = tid & 63, wave = tid >> 6;
  const int g = lane >> 4, lr = lane & 15;
  constexpr int MI = (BN == 128) ? 4 : 2;
  const int wm = (BN == 128) ? (wave >> 1) * 64 : wave * 32;
  const int wn = (BN == 128) ? (wave & 1) * 64 : 0;
  fv4 acc[MI][4] = {};
  const int srow = wave * 32 + (lane >> 2);
  const int sch = (lane & 3) * 8;
  const unsigned short* ga0 = A + (size_t)(m0 + srow) * K + sch;
  const int srowb = (BN == 128) ? srow : (wave * 16 + (lane >> 2));
  const unsigned short* gb0 = Bt + (size_t)(n0 + srowb) * K + sch;
  const int NIT = K >> 5;
  auto stage = [&](int k0, int pp) {
    unsigned short* lad = la[pp] + wave * 1024;
    unsigned short* lbd = lb[pp] + ((BN == 128) ? wave * 1024 : wave * 512);
    gld16(ga0 + k0, lad);
    gld16(ga0 + (size_t)16 * K + k0, lad + 512);
    gld16(gb0 + k0, lbd);
    if constexpr (BN == 128) gld16(gb0 + (size_t)16 * K + k0, lbd + 512);
  };
  stage(0, 0);
  for (int it = 0; it < NIT; ++it) {
    const int p = it & 1;
    if (it > 0) __builtin_amdgcn_s_barrier();
    if (it + 1 < NIT) {
      stage((it + 1) * 32, p ^ 1);
      if constexpr (BN == 128)
        asm volatile("s_waitcnt vmcnt(4)" ::: "memory");
      else
        asm volatile("s_waitcnt vmcnt(3)" ::: "memory");
    } else {
      asm volatile("s_waitcnt vmcnt(0)" ::: "memory");
    }
    __builtin_amdgcn_sched_barrier(0);
    __builtin_amdgcn_s_barrier();
    bv8 af[MI], bf[4];
#pragma unroll
    for (int mi = 0; mi < MI; ++mi)
      af[mi] = *(const bv8*)(la[p] + (wm + mi * 16 + lr) * 32 + g * 8);
#pragma unroll
    for (int ni = 0; ni < 4; ++ni)
      bf[ni] = *(const bv8*)(lb[p] + (wn + ni * 16 + lr) * 32 + g * 8);
    __builtin_amdgcn_s_setprio(1);
#pragma unroll
    for (int mi = 0; mi < MI; ++mi)
#pragma unroll
      for (int ni = 0; ni < 4; ++ni)
        acc[mi][ni] = __builtin_amdgcn_mfma_f32_16x16x32_bf16(af[mi], bf[ni], acc[mi][ni], 0, 0, 0);
    __builtin_amdgcn_s_setprio(0);
  }
#pragma unroll
  for (int mi = 0; mi < MI; ++mi) {
#pragma unroll
    for (int r = 0; r < 4; ++r) {
      size_t row = (size_t)(m0 + wm + mi * 16 + g * 4 + r);
#pragma unroll
      for (int ni = 0; ni < 4; ++ni) {
        int col = n0 + wn + ni * 16 + lr;
        float val = acc[mi][ni][r];
        if constexpr (OUT_BF16)
          ((unsigned short*)Cp)[row * N + col] = f2b(val);
        else
          ((float*)Cp)[row * N + col] = val;
      }
    }
  }
}

// ---------------- flash attention, sliding window 512 (R12-proven) ----------
// MQA-shared: block = 512 thr = 8 waves = 4 heads x 2 key-halves over a
// 32-q-row slab; K/V staged once serve all 4 heads. 32x32x16 MFMA, swapped
// operands (S^T = mfma(K,Q)), in-register P via manual pack +
// permlane32_swap. Softmax in exp2 domain (log2e folded into q); fixed max
// (|score*log2e| <= 23.1, Cauchy-Schwarz on RMSNorm'd vectors). K+V double-
// buffered via global_load_lds with both-sides XOR swizzle. Monolithic
// softmax block (R14's per-m2 interleave measured -10% — reverted).
__global__ __launch_bounds__(512, 2) void k_attn(const unsigned short* __restrict__ q,
    const unsigned short* __restrict__ kg, const unsigned short* __restrict__ vtg,
    unsigned short* __restrict__ att) {
  __shared__ __align__(16) char ldsbuf[133120];   // K/V tiles; reused as combine buf
  __shared__ float lsb[4][32];
  unsigned short* kt = (unsigned short*)ldsbuf;           // [2][64*256]
  unsigned short* vl = (unsigned short*)ldsbuf + 32768;   // [2][256*64]
  const int bid = blockIdx.x;
  const int gidx = (bid & 7) * 32 + (bid >> 3);
  const int b = gidx >> 7;
  const int i0 = (gidx & 127) * 32;
  const int tid = threadIdx.x, wave = tid >> 6, lane = tid & 63;
  const int h = wave >> 1, ks = wave & 1;
  const int hi = lane >> 5, l31 = lane & 31;
  bv8 qf[16];
  {
    const unsigned short* qp = q + ((size_t)(b * HH + h) * SS + i0 + l31) * 256;
#pragma unroll
    for (int m = 0; m < 16; ++m) qf[m] = *(const bv8*)(qp + m * 16 + hi * 8);
  }
  fv16 po[8] = {};
  float lsp = 0.f;
  const int t0 = (i0 >= WIN) ? ((i0 - WIN + 1) >> 6) : 0;
  const int t1 = i0 >> 6;
  const unsigned short* kb = kg + (size_t)b * SS * 256;
  const unsigned short* vb = vtg + (size_t)b * 256 * SS;
  auto stageK = [&](int t, int pp) {
    const unsigned short* kbase = kb + (size_t)t * 64 * 256;
    unsigned short* dst = kt + pp * 16384;
#pragma unroll
    for (int c = 0; c < 4; ++c) {
      int slot = c * 512 + tid;
      int row = slot >> 5, s = slot & 31;
      gld16(kbase + (size_t)row * 256 + ((s ^ (row & 7)) * 8),
            dst + (c * 512 + wave * 64) * 8);
    }
  };
  auto stageV = [&](int t, int pp) {
    const unsigned short* vbase = vb + (size_t)t * 64;
    unsigned short* dst = vl + pp * 16384;
#pragma unroll
    for (int c = 0; c < 4; ++c) {
      int slot = c * 512 + tid;
      int d_ = slot >> 3, s = slot & 7;
      gld16(vbase + (size_t)d_ * SS + ((s ^ (d_ & 7)) * 8),
            dst + (c * 512 + wave * 64) * 8);
    }
  };
  stageK(t0, 0); stageV(t0, 0);
  int p = 0;
  const int krow = ks * 32 + l31;
  const int krx = krow & 7;
  const int vrx = l31 & 7;
  const float FSUB = 16.5f * 1.44269504f;
  for (int t = t0; t <= t1; ++t) {
    __syncthreads();
    if (t < t1) { stageK(t + 1, p ^ 1); stageV(t + 1, p ^ 1); }
    fv16 sa = {};
    const unsigned short* ktp = kt + p * 16384 + krow * 256;
    __builtin_amdgcn_s_setprio(1);
#pragma unroll
    for (int m = 0; m < 16; ++m) {
      bv8 kf = *(const bv8*)(ktp + (((m * 2 + hi) ^ krx) * 8));
      sa = __builtin_amdgcn_mfma_f32_32x32x16_bf16(kf, qf[m], sa, 0, 0, 0);
    }
    __builtin_amdgcn_s_setprio(0);
    const int kb0 = t * 64 + ks * 32;
    const bool nm = (kb0 + 31 > i0) || (i0 + 31 - kb0 >= WIN);
    if (nm) {
      const int qa = i0 + l31;
#pragma unroll
      for (int r = 0; r < 16; ++r) {
        int j = kb0 + (r & 3) + 8 * (r >> 2) + 4 * hi;
        if (j > qa || qa - j >= WIN) sa[r] = -1e30f;
      }
    }
    unsigned a[8];
#pragma unroll
    for (int i = 0; i < 8; ++i) {
      float e0 = exp2f(sa[2 * i] - FSUB);
      float e1 = exp2f(sa[2 * i + 1] - FSUB);
      lsp += e0 + e1;
      a[i] = pk2(e0, e1);
    }
    const unsigned short* vlp = vl + p * 16384;
    __builtin_amdgcn_s_setprio(1);
#pragma unroll
    for (int m2 = 0; m2 < 2; ++m2) {
      auto r02 = __builtin_amdgcn_permlane32_swap(a[m2 * 4 + 0], a[m2 * 4 + 2], false, false);
      auto r13 = __builtin_amdgcn_permlane32_swap(a[m2 * 4 + 1], a[m2 * 4 + 3], false, false);
      union { unsigned u[4]; bv8 v; } pf;
      pf.u[0] = r02[0]; pf.u[1] = r13[0]; pf.u[2] = r02[1]; pf.u[3] = r13[1];
      const int slot = (ks * 4 + m2 * 2 + hi) ^ vrx;
#pragma unroll
      for (int ds_ = 0; ds_ < 8; ++ds_) {
        bv8 vf = *(const bv8*)(vlp + (ds_ * 32 + l31) * 64 + slot * 8);
        po[ds_] = __builtin_amdgcn_mfma_f32_32x32x16_bf16(vf, pf.v, po[ds_], 0, 0, 0);
      }
    }
    __builtin_amdgcn_s_setprio(0);
    p ^= 1;
  }
  float lsfull = lsp + __shfl_xor(lsp, 32, 64);
  __syncthreads();
  float* cb = (float*)ldsbuf;
  if (ks == 1) {
#pragma unroll
    for (int ds_ = 0; ds_ < 8; ++ds_)
#pragma unroll
      for (int j = 0; j < 4; ++j) {
        int d0 = ds_ * 32 + 8 * j + 4 * hi;
        fv4 v4; v4[0] = po[ds_][4 * j]; v4[1] = po[ds_][4 * j + 1];
        v4[2] = po[ds_][4 * j + 2]; v4[3] = po[ds_][4 * j + 3];
        *(fv4*)(cb + (h * 32 + l31) * 260 + d0) = v4;
      }
    if (lane < 32) lsb[h][lane] = lsfull;
  }
  __syncthreads();
  if (ks == 0) {
    float total = lsfull + lsb[h][l31];
    float inv = 1.0f / total;
    unsigned short* op = att + ((size_t)b * SS + i0 + l31) * 1024 + h * 256;
#pragma unroll
    for (int ds_ = 0; ds_ < 8; ++ds_)
#pragma unroll
      for (int j = 0; j < 4; ++j) {
        int d0 = ds_ * 32 + 8 * j + 4 * hi;
        fv4 v4 = *(const fv4*)(cb + (h * 32 + l31) * 260 + d0);
        ushort4 o;
        o.x = f2b((po[ds_][4 * j] + v4[0]) * inv);
        o.y = f2b((po[ds_][4 * j + 1] + v4[1]) * inv);
        o.z = f2b((po[ds_][4 * j + 2] + v4[2]) * inv);
        o.w = f2b((po[ds_][4 * j + 3] + v4[3]) * inv);
        *(ushort4*)(op + d0) = o;
      }
  }
}

extern "C" void kernel_launch(void* const* d_in, const int* in_sizes, int n_in,
                              void* d_out, int out_size, void* d_ws, size_t ws_size,
                              hipStream_t stream) {
  const float* x    = (const float*)d_in[0];
  // d_in[1] = mask (computed analytically)
  const float* cosp = (const float*)d_in[2];
  const float* sinp = (const float*)d_in[3];
  const float* Wq   = (const float*)d_in[4];
  const float* Wk   = (const float*)d_in[5];
  const float* Wv   = (const float*)d_in[6];
  const float* Wo   = (const float*)d_in[7];
  const float* qsc  = (const float*)d_in[8];
  const float* ksc  = (const float*)d_in[9];
  float* out = (float*)d_out;
  char* ws = (char*)d_ws;

  unsigned short* xb   = (unsigned short*)(ws);               // 8192x640 bf16
  unsigned short* wqkv = (unsigned short*)(ws + 10485760);    // 1536x640 bf16 (W^T)
  unsigned short* wo   = (unsigned short*)(ws + 12451840);    // 640x1024 bf16 (Wo^T)
  float*          ctab = (float*)(ws + 13762560);             // 4096x256 f32
  unsigned short* qb   = (unsigned short*)(ws + 38928384);    // (B,H,S,D) bf16
  unsigned short* kbuf = (unsigned short*)(ws + 55705600);    // (B,S,D) bf16
  unsigned short* vt   = (unsigned short*)(ws + 59899904);    // (B,D,S) bf16
  unsigned short* attb = (unsigned short*)(ws + 64094208);    // (B,S,H*D) bf16

  k_wtrans<<<dim3(32, 32, 6), 256, 0, stream>>>(Wq, Wk, Wv, Wo, cosp, sinp, x,
                                                wqkv, wo, ctab, xb);
  k_gemm_qkv<<<768, 256, 0, stream>>>(xb, wqkv, ctab, qsc, ksc, qb, kbuf, vt);
  k_attn<<<256, 512, 0, stream>>>(qb, kbuf, vt, attb);
  k_gemm<false, 64><<<640, 256, 0, stream>>>(attb, wo, out, 8192, 640, 1024, 10);
}